// Round 1
// 126.621 us; speedup vs baseline: 1.0130x; 1.0130x over previous
//
#include <hip/hip_runtime.h>

// B=8, T=2048, C=768, H=64. x fp32 [B,T,C]; Wq/Wk/Wv fp32 [C,H]; out fp32 [B,T,H].
// R11: native __bf16 casts (compiler emits v_cvt_pk_bf16_f32, RNE — replaces
//      3-op manual round-and-shift), softmax constant folding (1 FMA + exp +
//      select-0), __builtin_amdgcn_exp2f. Structure unchanged from R10.

typedef __bf16 bf16x8 __attribute__((ext_vector_type(8)));
typedef float  f32x4  __attribute__((ext_vector_type(4)));
typedef unsigned int u32;

union ABu {
    bf16x8 v;
    uint4  u;
    unsigned short us[8];
};

__device__ __forceinline__ unsigned short f2bf(float f) {
    union { __bf16 h; unsigned short s; } c;
    c.h = (__bf16)f;          // v_cvt_pk_bf16_f32 when paired by the compiler
    return c.s;
}
__device__ __forceinline__ float bf2f(unsigned short s) {
    union { unsigned int u; float f; } c; c.u = ((unsigned int)s) << 16;
    return c.f;
}

// async global->LDS, 16B per lane; dst must be wave-uniform base + lane*16
__device__ __forceinline__ void gld16(void* lds, const void* g) {
    __builtin_amdgcn_global_load_lds(
        (const u32 __attribute__((address_space(1)))*)g,
        (u32 __attribute__((address_space(3)))*)lds, 16, 0, 0);
}

// ---------------------------------------------------------------------------
// Kernel 1: W [768][64] fp32 -> wF fragment-major bf16.
// ---------------------------------------------------------------------------
__global__ __launch_bounds__(256)
void wt_kernel(const float* __restrict__ Wq, const float* __restrict__ Wk,
               const float* __restrict__ Wv, unsigned short* __restrict__ wF) {
    const int j   = blockIdx.x / 6;
    const int kgg = blockIdx.x % 6;
    const int t = threadIdx.x;
    const int kg = kgg * 4 + (t >> 6);
    const int lane = t & 63, quad = lane >> 4, l16 = lane & 15;
    const int m = j >> 2, nb = (j & 3) * 16;
    const float* W = (m == 0) ? Wq : (m == 1) ? Wk : Wv;
    ABu o;
#pragma unroll
    for (int i = 0; i < 8; ++i)
        o.us[i] = f2bf(W[(kg * 32 + quad * 8 + i) * 64 + nb + l16]);
    *(uint4*)(wF + ((size_t)(j * 24 + kg) * 64 + lane) * 8) = o.u;
}

// ---------------------------------------------------------------------------
// Kernel 2: QKV GEMM, double-buffered. 512 blocks x 512 threads (8 waves).
// One barrier per k-iteration; next W slice (global_load_lds) + x tile
// prefetched during compute. LDS 78.5 KB -> 2 blocks/CU.
// ---------------------------------------------------------------------------
__global__ __launch_bounds__(512, 4)
void qkv_kernel(const float* __restrict__ x, const unsigned short* __restrict__ wF,
                unsigned short* __restrict__ qF, unsigned short* __restrict__ kF,
                unsigned short* __restrict__ vF) {
    __shared__ float          xs[2][32][68];          // 17.4 KB
    __shared__ unsigned short wsW[2][24][64][8];      // 48 KB
    __shared__ unsigned short Cst[2][12][16][17];     // 13.1 KB
    const int tid  = threadIdx.x;
    const int lane = tid & 63, w = tid >> 6;
    const int l16  = lane & 15, quad = lane >> 4;
    const int mh   = w & 1, nh = w >> 1;
    const int m0   = blockIdx.x * 32;
    const int b    = m0 >> 11;

    f32x4 acc[3];
#pragma unroll
    for (int j = 0; j < 3; ++j) acc[j] = (f32x4){0.f, 0.f, 0.f, 0.f};

    const int xrow = tid >> 4, xc16 = tid & 15;       // 512 thr = 32 rows x 16 float4

    // prologue: stage iter 0 into buffer 0
#pragma unroll
    for (int i = 0; i < 3; ++i) {
        const int c = w * 3 + i, j = c >> 1, kg2 = c & 1;
        gld16((char*)wsW[0] + (size_t)c * 1024 + lane * 16,
              (const char*)wF + ((size_t)(j * 24 + kg2) * 64 + lane) * 16);
    }
    *(float4*)&xs[0][xrow][xc16 * 4] =
        *(const float4*)&x[(size_t)(m0 + xrow) * 768 + xc16 * 4];
    __syncthreads();

    for (int kk = 0; kk < 12; ++kk) {
        const int cur = kk & 1, nxt = cur ^ 1;
        float4 xn;
        if (kk + 1 < 12) {
            // prefetch next W slice (async -> LDS) and next x tile (-> regs)
#pragma unroll
            for (int i = 0; i < 3; ++i) {
                const int c = w * 3 + i, j = c >> 1, kg2 = c & 1;
                gld16((char*)wsW[nxt] + (size_t)c * 1024 + lane * 16,
                      (const char*)wF + ((size_t)(j * 24 + (kk + 1) * 2 + kg2) * 64 + lane) * 16);
            }
            xn = *(const float4*)&x[(size_t)(m0 + xrow) * 768 + (kk + 1) * 64 + xc16 * 4];
        }

        // compute current buffer
#pragma unroll
        for (int kg2 = 0; kg2 < 2; ++kg2) {
            const float* xr = &xs[cur][mh * 16 + l16][kg2 * 32 + quad * 8];
            float4 f0 = *(const float4*)xr;
            float4 f1 = *(const float4*)(xr + 4);
            ABu af;
            af.us[0] = f2bf(f0.x); af.us[1] = f2bf(f0.y);
            af.us[2] = f2bf(f0.z); af.us[3] = f2bf(f0.w);
            af.us[4] = f2bf(f1.x); af.us[5] = f2bf(f1.y);
            af.us[6] = f2bf(f1.z); af.us[7] = f2bf(f1.w);
#pragma unroll
            for (int jl = 0; jl < 3; ++jl) {
                const int j = nh * 3 + jl;
                ABu bf;
                bf.u = *(const uint4*)((char*)wsW[cur] + (size_t)(j * 2 + kg2) * 1024 + lane * 16);
                acc[jl] = __builtin_amdgcn_mfma_f32_16x16x32_bf16(af.v, bf.v, acc[jl], 0, 0, 0);
            }
        }

        if (kk + 1 < 12)
            *(float4*)&xs[nxt][xrow][xc16 * 4] = xn;   // waitcnt lands here, post-compute
        __syncthreads();   // drains prefetch; protects cur for next overwrite
    }

    // ---- epilogue: C-frags -> Cst (bf16) -> fragment-major stores ----
#pragma unroll
    for (int jl = 0; jl < 3; ++jl)
#pragma unroll
        for (int r = 0; r < 4; ++r)
            Cst[mh][nh * 3 + jl][quad * 4 + r][l16] = f2bf(acc[jl][r]);
    __syncthreads();

    const int g = tid >> 6, el = tid & 63;
    const int eq = el >> 4, e16 = el & 15;
    if (g < 4) {   // Q and K frags
        const int mhh = g >> 1, kg = g & 1;
        ABu oq, ok;
#pragma unroll
        for (int i = 0; i < 8; ++i) {
            const int h = kg * 32 + eq * 8 + i;
            oq.us[i] = Cst[mhh][h >> 4][e16][h & 15];
            ok.us[i] = Cst[mhh][4 + (h >> 4)][e16][h & 15];
        }
        const size_t tt = (size_t)b * 128 + ((m0 & 2047) >> 4) + mhh;
        *(uint4*)(qF + ((tt * 2 + kg) * 64 + el) * 8) = oq.u;
        *(uint4*)(kF + ((tt * 2 + kg) * 64 + el) * 8) = ok.u;
    } else {       // V frags
        const int nt = g & 3;
        const int sv = (m0 & 2047) >> 6, kg = (m0 >> 5) & 1;
        ABu ov;
#pragma unroll
        for (int i = 0; i < 8; ++i) {
            const int loc = eq * 8 + i;
            ov.us[i] = Cst[loc >> 4][8 + nt][loc & 15][e16];
        }
        *(uint4*)(vF + ((((size_t)(b * 32 + sv) * 4 + nt) * 2 + kg) * 64 + el) * 8) = ov.u;
    }
}

// ---------------------------------------------------------------------------
// Kernel 3: flash attention, barrier-free (R8 body). 1024 blocks x 256 thr.
// Frag-major K/V loaded directly (coalesced 1KB/instr); fixed-max softmax
// (scale+max folded into one FMA const, select-0 after exp); bf16 partial-O
// + fp32 partial-l to private buffers.
// ---------------------------------------------------------------------------
__global__ __launch_bounds__(256, 4)
void attn_kernel(const unsigned short* __restrict__ qF,
                 const unsigned short* __restrict__ kF,
                 const unsigned short* __restrict__ vF,
                 unsigned short* __restrict__ opart, float* __restrict__ lpart) {
    __shared__ unsigned short PT[4][64][20];
    const int tid  = threadIdx.x;
    const int lane = tid & 63, w = tid >> 6;
    const int l16  = lane & 15, quad = lane >> 4;
    const int idx  = blockIdx.x;
    const int b    = idx >> 7;
    const int rem  = idx & 127;
    const int jj   = rem >> 2, quarter = rem & 3;
    const int qs   = (jj & 1) ? (31 - (jj >> 1)) : (jj >> 1);   // heavy/light interleave
    const int tt   = qs * 4 + w;
    const int tq0  = tt * 16;
    const float SC = 0.125f * 1.44269504089f;   // scale * log2(e)
    const float MB = 16.0f  * 1.44269504089f;   // fixed-max * log2(e)

    ABu aq[2];
#pragma unroll
    for (int kg = 0; kg < 2; ++kg)
        aq[kg].u = *(const uint4*)(qF + ((((size_t)b * 128 + tt) * 2 + kg) * 64 + lane) * 8);

    f32x4 acc[4];
#pragma unroll
    for (int nt = 0; nt < 4; ++nt) acc[nt] = (f32x4){0.f, 0.f, 0.f, 0.f};
    float lrow[4] = {0.f, 0.f, 0.f, 0.f};

    for (int st = quarter; st <= qs; st += 4) {
        const int s0 = st * 64;
        const unsigned short* kbase = kF + (size_t)(b * 128 + st * 4) * 1024;
        const unsigned short* vbase = vF + (size_t)(b * 32 + st) * 4096;
        ABu kf[8];
#pragma unroll
        for (int c = 0; c < 8; ++c)
            kf[c].u = *(const uint4*)(kbase + (size_t)c * 512 + lane * 8);
        float p[4][4];
#pragma unroll
        for (int nt = 0; nt < 4; ++nt) {
            f32x4 s = (f32x4){0.f, 0.f, 0.f, 0.f};
            s = __builtin_amdgcn_mfma_f32_16x16x32_bf16(aq[0].v, kf[nt * 2 + 0].v, s, 0, 0, 0);
            s = __builtin_amdgcn_mfma_f32_16x16x32_bf16(aq[1].v, kf[nt * 2 + 1].v, s, 0, 0, 0);
            const int sg = s0 + nt * 16 + l16;
#pragma unroll
            for (int r = 0; r < 4; ++r) {
                float pv = __builtin_amdgcn_exp2f(__builtin_fmaf(s[r], SC, -MB));
                pv = (sg > tq0 + quad * 4 + r) ? 0.f : pv;
                p[nt][r] = pv;
                lrow[r] += pv;
            }
        }
        ABu vf[8];
#pragma unroll
        for (int c = 0; c < 8; ++c)
            vf[c].u = *(const uint4*)(vbase + (size_t)c * 512 + lane * 8);
#pragma unroll
        for (int nt = 0; nt < 4; ++nt) {
            ushort4 pw;
            pw.x = f2bf(p[nt][0]); pw.y = f2bf(p[nt][1]);
            pw.z = f2bf(p[nt][2]); pw.w = f2bf(p[nt][3]);
            *(ushort4*)&PT[w][nt * 16 + l16][quad * 4] = pw;
        }
        ABu ap[2];
#pragma unroll
        for (int ks = 0; ks < 2; ++ks)
#pragma unroll
            for (int j = 0; j < 8; ++j)
                ap[ks].us[j] = PT[w][ks * 32 + quad * 8 + j][l16];
#pragma unroll
        for (int nt = 0; nt < 4; ++nt) {
            acc[nt] = __builtin_amdgcn_mfma_f32_16x16x32_bf16(ap[0].v, vf[nt * 2 + 0].v, acc[nt], 0, 0, 0);
            acc[nt] = __builtin_amdgcn_mfma_f32_16x16x32_bf16(ap[1].v, vf[nt * 2 + 1].v, acc[nt], 0, 0, 0);
        }
    }

    // ---- epilogue: bf16 partial-O, fp32 partial-l ----
#pragma unroll
    for (int off = 1; off <= 8; off <<= 1)
#pragma unroll
        for (int r = 0; r < 4; ++r)
            lrow[r] += __shfl_xor(lrow[r], off);

    unsigned short* obase = opart + ((size_t)(quarter * 8 + b) * 2048 + tq0) * 64;
#pragma unroll
    for (int nt = 0; nt < 4; ++nt)
#pragma unroll
        for (int r = 0; r < 4; ++r)
            obase[(size_t)(quad * 4 + r) * 64 + nt * 16 + l16] = f2bf(acc[nt][r]);
    if (l16 == 0) {
#pragma unroll
        for (int r = 0; r < 4; ++r)
            lpart[(size_t)(quarter * 8 + b) * 2048 + tq0 + quad * 4 + r] = lrow[r];
    }
}

// ---------------------------------------------------------------------------
// Kernel 4: finalize — out = (sum of 4 bf16 partial O) / (sum of 4 partial l).
// ---------------------------------------------------------------------------
__global__ __launch_bounds__(256)
void finalize_kernel(const unsigned short* __restrict__ opart,
                     const float* __restrict__ lpart, float* __restrict__ out) {
    const int idx = blockIdx.x * 256 + threadIdx.x;     // 4-elem group, 262144 total
    const int row = idx >> 4;
    float4 v = (float4){0.f, 0.f, 0.f, 0.f};
    float  l = 0.f;
#pragma unroll
    for (int q = 0; q < 4; ++q) {
        ushort4 u = ((const ushort4*)opart)[(size_t)q * 262144 + idx];
        v.x += bf2f(u.x); v.y += bf2f(u.y); v.z += bf2f(u.z); v.w += bf2f(u.w);
        l += lpart[(size_t)q * 16384 + row];
    }
    const float li = 1.f / l;
    v.x *= li; v.y *= li; v.z *= li; v.w *= li;
    ((float4*)out)[idx] = v;
}

// ---------------------------------------------------------------------------
extern "C" void kernel_launch(void* const* d_in, const int* in_sizes, int n_in,
                              void* d_out, int out_size, void* d_ws, size_t ws_size,
                              hipStream_t stream) {
    const float* x  = (const float*)d_in[0];
    const float* Wq = (const float*)d_in[1];
    const float* Wk = (const float*)d_in[2];
    const float* Wv = (const float*)d_in[3];
    float* out = (float*)d_out;

    char* ws = (char*)d_ws;
    unsigned short* wF    = (unsigned short*)ws;                              // 288 KB
    unsigned short* qF    = (unsigned short*)(ws + (512 << 10));              // 2 MB
    unsigned short* kF    = (unsigned short*)(ws + (512 << 10) + (2 << 20));  // 2 MB
    unsigned short* vF    = (unsigned short*)(ws + (512 << 10) + (4 << 20));  // 2 MB
    unsigned short* opart = (unsigned short*)(ws + (512 << 10) + (6 << 20));  // 8 MB bf16
    float*          lpart = (float*)(ws + (512 << 10) + (14 << 20));          // 256 KB

    wt_kernel<<<72, 256, 0, stream>>>(Wq, Wk, Wv, wF);
    qkv_kernel<<<512, 512, 0, stream>>>(x, wF, qF, kF, vF);
    attn_kernel<<<1024, 256, 0, stream>>>(qF, kF, vF, opart, lpart);
    finalize_kernel<<<1024, 256, 0, stream>>>(opart, lpart, out);
}

// Round 2
// 122.242 us; speedup vs baseline: 1.0493x; 1.0358x over previous
//
#include <hip/hip_runtime.h>

// B=8, T=2048, C=768, H=64. x fp32 [B,T,C]; Wq/Wk/Wv fp32 [C,H]; out fp32 [B,T,H].
// R12: attn rewritten with swapped QK^T (S^T layout, q = lane&15) so the PV
//      A-operand is built in-register via v_cvt_pk_bf16_f32 + permlane{32,16}_swap
//      (no LDS P round-trip; PT array deleted). Causal mask paid only on the
//      diagonal tile (st == qs). qkv A-frag pack via explicit cvt_pk.

typedef __bf16 bf16x8 __attribute__((ext_vector_type(8)));
typedef float  f32x4  __attribute__((ext_vector_type(4)));
typedef unsigned int u32;

union ABu {
    bf16x8 v;
    uint4  u;
    unsigned short us[8];
};

__device__ __forceinline__ unsigned short f2bf(float f) {
    union { __bf16 h; unsigned short s; } c;
    c.h = (__bf16)f;          // RNE
    return c.s;
}
__device__ __forceinline__ float bf2f(unsigned short s) {
    union { unsigned int u; float f; } c; c.u = ((unsigned int)s) << 16;
    return c.f;
}
// packed fp32x2 -> bf16x2 (RNE), low half = lo
__device__ __forceinline__ u32 cvtpk_bf16(float lo, float hi) {
    u32 r;
    asm("v_cvt_pk_bf16_f32 %0, %1, %2" : "=v"(r) : "v"(lo), "v"(hi));
    return r;
}

// async global->LDS, 16B per lane; dst must be wave-uniform base + lane*16
__device__ __forceinline__ void gld16(void* lds, const void* g) {
    __builtin_amdgcn_global_load_lds(
        (const u32 __attribute__((address_space(1)))*)g,
        (u32 __attribute__((address_space(3)))*)lds, 16, 0, 0);
}

// ---------------------------------------------------------------------------
// Kernel 1: W [768][64] fp32 -> wF fragment-major bf16.
// ---------------------------------------------------------------------------
__global__ __launch_bounds__(256)
void wt_kernel(const float* __restrict__ Wq, const float* __restrict__ Wk,
               const float* __restrict__ Wv, unsigned short* __restrict__ wF) {
    const int j   = blockIdx.x / 6;
    const int kgg = blockIdx.x % 6;
    const int t = threadIdx.x;
    const int kg = kgg * 4 + (t >> 6);
    const int lane = t & 63, quad = lane >> 4, l16 = lane & 15;
    const int m = j >> 2, nb = (j & 3) * 16;
    const float* W = (m == 0) ? Wq : (m == 1) ? Wk : Wv;
    ABu o;
#pragma unroll
    for (int i = 0; i < 8; ++i)
        o.us[i] = f2bf(W[(kg * 32 + quad * 8 + i) * 64 + nb + l16]);
    *(uint4*)(wF + ((size_t)(j * 24 + kg) * 64 + lane) * 8) = o.u;
}

// ---------------------------------------------------------------------------
// Kernel 2: QKV GEMM, double-buffered. 512 blocks x 512 threads (8 waves).
// ---------------------------------------------------------------------------
__global__ __launch_bounds__(512, 4)
void qkv_kernel(const float* __restrict__ x, const unsigned short* __restrict__ wF,
                unsigned short* __restrict__ qF, unsigned short* __restrict__ kF,
                unsigned short* __restrict__ vF) {
    __shared__ float          xs[2][32][68];          // 17.4 KB
    __shared__ unsigned short wsW[2][24][64][8];      // 48 KB
    __shared__ unsigned short Cst[2][12][16][17];     // 13.1 KB
    const int tid  = threadIdx.x;
    const int lane = tid & 63, w = tid >> 6;
    const int l16  = lane & 15, quad = lane >> 4;
    const int mh   = w & 1, nh = w >> 1;
    const int m0   = blockIdx.x * 32;
    const int b    = m0 >> 11;

    f32x4 acc[3];
#pragma unroll
    for (int j = 0; j < 3; ++j) acc[j] = (f32x4){0.f, 0.f, 0.f, 0.f};

    const int xrow = tid >> 4, xc16 = tid & 15;       // 512 thr = 32 rows x 16 float4

    // prologue: stage iter 0 into buffer 0
#pragma unroll
    for (int i = 0; i < 3; ++i) {
        const int c = w * 3 + i, j = c >> 1, kg2 = c & 1;
        gld16((char*)wsW[0] + (size_t)c * 1024 + lane * 16,
              (const char*)wF + ((size_t)(j * 24 + kg2) * 64 + lane) * 16);
    }
    *(float4*)&xs[0][xrow][xc16 * 4] =
        *(const float4*)&x[(size_t)(m0 + xrow) * 768 + xc16 * 4];
    __syncthreads();

    for (int kk = 0; kk < 12; ++kk) {
        const int cur = kk & 1, nxt = cur ^ 1;
        float4 xn;
        if (kk + 1 < 12) {
            // prefetch next W slice (async -> LDS) and next x tile (-> regs)
#pragma unroll
            for (int i = 0; i < 3; ++i) {
                const int c = w * 3 + i, j = c >> 1, kg2 = c & 1;
                gld16((char*)wsW[nxt] + (size_t)c * 1024 + lane * 16,
                      (const char*)wF + ((size_t)(j * 24 + (kk + 1) * 2 + kg2) * 64 + lane) * 16);
            }
            xn = *(const float4*)&x[(size_t)(m0 + xrow) * 768 + (kk + 1) * 64 + xc16 * 4];
        }

        // compute current buffer
#pragma unroll
        for (int kg2 = 0; kg2 < 2; ++kg2) {
            const float* xr = &xs[cur][mh * 16 + l16][kg2 * 32 + quad * 8];
            float4 f0 = *(const float4*)xr;
            float4 f1 = *(const float4*)(xr + 4);
            ABu af;
            af.u.x = cvtpk_bf16(f0.x, f0.y);
            af.u.y = cvtpk_bf16(f0.z, f0.w);
            af.u.z = cvtpk_bf16(f1.x, f1.y);
            af.u.w = cvtpk_bf16(f1.z, f1.w);
#pragma unroll
            for (int jl = 0; jl < 3; ++jl) {
                const int j = nh * 3 + jl;
                ABu bf;
                bf.u = *(const uint4*)((char*)wsW[cur] + (size_t)(j * 2 + kg2) * 1024 + lane * 16);
                acc[jl] = __builtin_amdgcn_mfma_f32_16x16x32_bf16(af.v, bf.v, acc[jl], 0, 0, 0);
            }
        }

        if (kk + 1 < 12)
            *(float4*)&xs[nxt][xrow][xc16 * 4] = xn;   // waitcnt lands here, post-compute
        __syncthreads();   // drains prefetch; protects cur for next overwrite
    }

    // ---- epilogue: C-frags -> Cst (bf16) -> fragment-major stores ----
#pragma unroll
    for (int jl = 0; jl < 3; ++jl)
#pragma unroll
        for (int r = 0; r < 4; ++r)
            Cst[mh][nh * 3 + jl][quad * 4 + r][l16] = f2bf(acc[jl][r]);
    __syncthreads();

    const int g = tid >> 6, el = tid & 63;
    const int eq = el >> 4, e16 = el & 15;
    if (g < 4) {   // Q and K frags
        const int mhh = g >> 1, kg = g & 1;
        ABu oq, ok;
#pragma unroll
        for (int i = 0; i < 8; ++i) {
            const int h = kg * 32 + eq * 8 + i;
            oq.us[i] = Cst[mhh][h >> 4][e16][h & 15];
            ok.us[i] = Cst[mhh][4 + (h >> 4)][e16][h & 15];
        }
        const size_t tt = (size_t)b * 128 + ((m0 & 2047) >> 4) + mhh;
        *(uint4*)(qF + ((tt * 2 + kg) * 64 + el) * 8) = oq.u;
        *(uint4*)(kF + ((tt * 2 + kg) * 64 + el) * 8) = ok.u;
    } else {       // V frags
        const int nt = g & 3;
        const int sv = (m0 & 2047) >> 6, kg = (m0 >> 5) & 1;
        ABu ov;
#pragma unroll
        for (int i = 0; i < 8; ++i) {
            const int loc = eq * 8 + i;
            ov.us[i] = Cst[loc >> 4][8 + nt][loc & 15][e16];
        }
        *(uint4*)(vF + ((((size_t)(b * 32 + sv) * 4 + nt) * 2 + kg) * 64 + el) * 8) = ov.u;
    }
}

// ---------------------------------------------------------------------------
// Kernel 3: flash attention, barrier-free, zero-LDS. 1024 blocks x 256 thr.
// Swapped QK^T: S^T = mfma(K_frag, Q_frag) -> lane holds P[q=l16][s-slice].
// PV A-operand built in-register: cvt_pk + permlane32_swap + permlane16_swap.
// Mask applied only on the diagonal tile.
// ---------------------------------------------------------------------------
template<bool MASKED>
__device__ __forceinline__ void attn_tile(
    const int st, const int b, const int tq0,
    const int lane, const int l16, const int quad,
    const ABu& aq0, const ABu& aq1,
    const unsigned short* __restrict__ kF,
    const unsigned short* __restrict__ vF,
    f32x4 acc[4], float& lsum)
{
    const float SC = 0.125f * 1.44269504089f;   // scale * log2(e)
    const float MB = 16.0f  * 1.44269504089f;   // fixed-max * log2(e)
    const int s0 = st * 64;
    const unsigned short* kbase = kF + (size_t)(b * 128 + st * 4) * 1024;
    const unsigned short* vbase = vF + (size_t)(b * 32 + st) * 4096;

    ABu kf[8];
#pragma unroll
    for (int c = 0; c < 8; ++c)
        kf[c].u = *(const uint4*)(kbase + (size_t)c * 512 + lane * 8);

    float p[4][4];
#pragma unroll
    for (int nt = 0; nt < 4; ++nt) {
        f32x4 s = (f32x4){0.f, 0.f, 0.f, 0.f};
        // swapped operands: A = K-frag (rows = s), B = Q-frag (cols = q)
        s = __builtin_amdgcn_mfma_f32_16x16x32_bf16(kf[nt * 2 + 0].v, aq0.v, s, 0, 0, 0);
        s = __builtin_amdgcn_mfma_f32_16x16x32_bf16(kf[nt * 2 + 1].v, aq1.v, s, 0, 0, 0);
#pragma unroll
        for (int r = 0; r < 4; ++r) {
            float pv = __builtin_amdgcn_exp2f(__builtin_fmaf(s[r], SC, -MB));
            if (MASKED)
                pv = (s0 + nt * 16 + quad * 4 + r > tq0 + l16) ? 0.f : pv;
            p[nt][r] = pv;
            lsum += pv;
        }
    }

    ABu vf[8];
#pragma unroll
    for (int c = 0; c < 8; ++c)
        vf[c].u = *(const uint4*)(vbase + (size_t)c * 512 + lane * 8);

    // P (S^T C-layout) -> PV A-frags, fully in-register.
    // Target: af[ks].us[j] = P[q=l16][s = ks*32 + quad*8 + j].
    // permlane32_swap(X,Y):  X<-[X01,Y01], Y<-[X23,Y23]   (16-lane groups)
    // permlane16_swap(X,Y):  X<-[X0,Y0,X2,Y2], Y<-[X1,Y1,X3,Y3]
    // composition on (Xw,Yw): first -> [X0,X2,Y0,Y2] (w0), second -> [X1,X3,Y1,Y3] (w2)
    ABu af[2];
#pragma unroll
    for (int ks = 0; ks < 2; ++ks) {
        u32 x0 = cvtpk_bf16(p[2 * ks][0], p[2 * ks][1]);
        u32 x1 = cvtpk_bf16(p[2 * ks][2], p[2 * ks][3]);
        u32 y0 = cvtpk_bf16(p[2 * ks + 1][0], p[2 * ks + 1][1]);
        u32 y1 = cvtpk_bf16(p[2 * ks + 1][2], p[2 * ks + 1][3]);
        asm("v_permlane32_swap_b32 %0, %1" : "+v"(x0), "+v"(y0));
        asm("v_permlane16_swap_b32 %0, %1" : "+v"(x0), "+v"(y0));
        asm("v_permlane32_swap_b32 %0, %1" : "+v"(x1), "+v"(y1));
        asm("v_permlane16_swap_b32 %0, %1" : "+v"(x1), "+v"(y1));
        af[ks].u = (uint4){x0, x1, y0, y1};
    }

#pragma unroll
    for (int nt = 0; nt < 4; ++nt) {
        acc[nt] = __builtin_amdgcn_mfma_f32_16x16x32_bf16(af[0].v, vf[nt * 2 + 0].v, acc[nt], 0, 0, 0);
        acc[nt] = __builtin_amdgcn_mfma_f32_16x16x32_bf16(af[1].v, vf[nt * 2 + 1].v, acc[nt], 0, 0, 0);
    }
}

__global__ __launch_bounds__(256, 4)
void attn_kernel(const unsigned short* __restrict__ qF,
                 const unsigned short* __restrict__ kF,
                 const unsigned short* __restrict__ vF,
                 unsigned short* __restrict__ opart, float* __restrict__ lpart) {
    const int tid  = threadIdx.x;
    const int lane = tid & 63, w = tid >> 6;
    const int l16  = lane & 15, quad = lane >> 4;
    const int idx  = blockIdx.x;
    const int b    = idx >> 7;
    const int rem  = idx & 127;
    const int jj   = rem >> 2, quarter = rem & 3;
    const int qs   = (jj & 1) ? (31 - (jj >> 1)) : (jj >> 1);   // heavy/light interleave
    const int tt   = qs * 4 + w;
    const int tq0  = tt * 16;

    ABu aq0, aq1;
    aq0.u = *(const uint4*)(qF + ((((size_t)b * 128 + tt) * 2 + 0) * 64 + lane) * 8);
    aq1.u = *(const uint4*)(qF + ((((size_t)b * 128 + tt) * 2 + 1) * 64 + lane) * 8);

    f32x4 acc[4];
#pragma unroll
    for (int nt = 0; nt < 4; ++nt) acc[nt] = (f32x4){0.f, 0.f, 0.f, 0.f};
    float lsum = 0.f;

    int st = quarter;
    for (; st < qs; st += 4)
        attn_tile<false>(st, b, tq0, lane, l16, quad, aq0, aq1, kF, vF, acc, lsum);
    if (st == qs)
        attn_tile<true>(st, b, tq0, lane, l16, quad, aq0, aq1, kF, vF, acc, lsum);

    // ---- epilogue: bf16 partial-O, fp32 partial-l ----
    // lsum per lane covers its (nt,r) s-slices for q = l16; reduce across quads.
    lsum += __shfl_xor(lsum, 16);
    lsum += __shfl_xor(lsum, 32);

    unsigned short* obase = opart + ((size_t)(quarter * 8 + b) * 2048 + tq0) * 64;
#pragma unroll
    for (int nt = 0; nt < 4; ++nt)
#pragma unroll
        for (int r = 0; r < 4; ++r)
            obase[(size_t)(quad * 4 + r) * 64 + nt * 16 + l16] = f2bf(acc[nt][r]);
    if (lane < 16)
        lpart[(size_t)(quarter * 8 + b) * 2048 + tq0 + lane] = lsum;
}

// ---------------------------------------------------------------------------
// Kernel 4: finalize — out = (sum of 4 bf16 partial O) / (sum of 4 partial l).
// ---------------------------------------------------------------------------
__global__ __launch_bounds__(256)
void finalize_kernel(const unsigned short* __restrict__ opart,
                     const float* __restrict__ lpart, float* __restrict__ out) {
    const int idx = blockIdx.x * 256 + threadIdx.x;     // 4-elem group, 262144 total
    const int row = idx >> 4;
    float4 v = (float4){0.f, 0.f, 0.f, 0.f};
    float  l = 0.f;
#pragma unroll
    for (int q = 0; q < 4; ++q) {
        ushort4 u = ((const ushort4*)opart)[(size_t)q * 262144 + idx];
        v.x += bf2f(u.x); v.y += bf2f(u.y); v.z += bf2f(u.z); v.w += bf2f(u.w);
        l += lpart[(size_t)q * 16384 + row];
    }
    const float li = 1.f / l;
    v.x *= li; v.y *= li; v.z *= li; v.w *= li;
    ((float4*)out)[idx] = v;
}

// ---------------------------------------------------------------------------
extern "C" void kernel_launch(void* const* d_in, const int* in_sizes, int n_in,
                              void* d_out, int out_size, void* d_ws, size_t ws_size,
                              hipStream_t stream) {
    const float* x  = (const float*)d_in[0];
    const float* Wq = (const float*)d_in[1];
    const float* Wk = (const float*)d_in[2];
    const float* Wv = (const float*)d_in[3];
    float* out = (float*)d_out;

    char* ws = (char*)d_ws;
    unsigned short* wF    = (unsigned short*)ws;                              // 288 KB
    unsigned short* qF    = (unsigned short*)(ws + (512 << 10));              // 2 MB
    unsigned short* kF    = (unsigned short*)(ws + (512 << 10) + (2 << 20));  // 2 MB
    unsigned short* vF    = (unsigned short*)(ws + (512 << 10) + (4 << 20));  // 2 MB
    unsigned short* opart = (unsigned short*)(ws + (512 << 10) + (6 << 20));  // 8 MB bf16
    float*          lpart = (float*)(ws + (512 << 10) + (14 << 20));          // 256 KB

    wt_kernel<<<72, 256, 0, stream>>>(Wq, Wk, Wv, wF);
    qkv_kernel<<<512, 512, 0, stream>>>(x, wF, qF, kF, vF);
    attn_kernel<<<1024, 256, 0, stream>>>(qF, kF, vF, opart, lpart);
    finalize_kernel<<<1024, 256, 0, stream>>>(opart, lpart, out);
}

// Round 4
// 117.331 us; speedup vs baseline: 1.0932x; 1.0419x over previous
//
#include <hip/hip_runtime.h>

// B=8, T=2048, C=768, H=64. x fp32 [B,T,C]; Wq/Wk/Wv fp32 [C,H]; out fp32 [B,T,H].
// R13 (resubmit; prior run died to container-acquisition failure, not a kernel
// verdict): (a) attn XCD-balanced block mapping — old map put qs<=15 on XCDs
//      0-3 and qs>=16 on XCDs 4-7 (2.9x work skew); new map: b = XCD (K/V
//      L2-resident), each CU gets qs set {v,31-v,v+8,23-v} x 4 quarters.
//      (b) qkv stages x as bf16 in LDS (convert once; -8 cvtpk, -2 ds_read/iter).
//      (c) attn row-sum via ones-MFMA into spare acc (kills 16 adds + shuffles).

typedef __bf16 bf16x8 __attribute__((ext_vector_type(8)));
typedef float  f32x4  __attribute__((ext_vector_type(4)));
typedef unsigned int u32;

union ABu {
    bf16x8 v;
    uint4  u;
    unsigned short us[8];
};

__device__ __forceinline__ unsigned short f2bf(float f) {
    union { __bf16 h; unsigned short s; } c;
    c.h = (__bf16)f;          // RNE
    return c.s;
}
__device__ __forceinline__ float bf2f(unsigned short s) {
    union { unsigned int u; float f; } c; c.u = ((unsigned int)s) << 16;
    return c.f;
}
// packed fp32x2 -> bf16x2 (RNE), low half = lo
__device__ __forceinline__ u32 cvtpk_bf16(float lo, float hi) {
    u32 r;
    asm("v_cvt_pk_bf16_f32 %0, %1, %2" : "=v"(r) : "v"(lo), "v"(hi));
    return r;
}

// async global->LDS, 16B per lane; dst must be wave-uniform base + lane*16
__device__ __forceinline__ void gld16(void* lds, const void* g) {
    __builtin_amdgcn_global_load_lds(
        (const u32 __attribute__((address_space(1)))*)g,
        (u32 __attribute__((address_space(3)))*)lds, 16, 0, 0);
}

// ---------------------------------------------------------------------------
// Kernel 1: W [768][64] fp32 -> wF fragment-major bf16.
// ---------------------------------------------------------------------------
__global__ __launch_bounds__(256)
void wt_kernel(const float* __restrict__ Wq, const float* __restrict__ Wk,
               const float* __restrict__ Wv, unsigned short* __restrict__ wF) {
    const int j   = blockIdx.x / 6;
    const int kgg = blockIdx.x % 6;
    const int t = threadIdx.x;
    const int kg = kgg * 4 + (t >> 6);
    const int lane = t & 63, quad = lane >> 4, l16 = lane & 15;
    const int m = j >> 2, nb = (j & 3) * 16;
    const float* W = (m == 0) ? Wq : (m == 1) ? Wk : Wv;
    ABu o;
#pragma unroll
    for (int i = 0; i < 8; ++i)
        o.us[i] = f2bf(W[(kg * 32 + quad * 8 + i) * 64 + nb + l16]);
    *(uint4*)(wF + ((size_t)(j * 24 + kg) * 64 + lane) * 8) = o.u;
}

// ---------------------------------------------------------------------------
// Kernel 2: QKV GEMM, double-buffered. 512 blocks x 512 threads (8 waves).
// x staged in LDS as bf16 (single conversion at staging). LDS 70.3 KB -> 2/CU.
// ---------------------------------------------------------------------------
__global__ __launch_bounds__(512, 4)
void qkv_kernel(const float* __restrict__ x, const unsigned short* __restrict__ wF,
                unsigned short* __restrict__ qF, unsigned short* __restrict__ kF,
                unsigned short* __restrict__ vF) {
    __shared__ unsigned short xs[2][32][72];          // 9.2 KB bf16 (144B rows, 16B-aligned)
    __shared__ unsigned short wsW[2][24][64][8];      // 48 KB
    __shared__ unsigned short Cst[2][12][16][17];     // 13.1 KB
    const int tid  = threadIdx.x;
    const int lane = tid & 63, w = tid >> 6;
    const int l16  = lane & 15, quad = lane >> 4;
    const int mh   = w & 1, nh = w >> 1;
    const int m0   = blockIdx.x * 32;
    const int b    = m0 >> 11;

    f32x4 acc[3];
#pragma unroll
    for (int j = 0; j < 3; ++j) acc[j] = (f32x4){0.f, 0.f, 0.f, 0.f};

    const int xrow = tid >> 4, xc16 = tid & 15;       // 512 thr = 32 rows x 16 float4

    // prologue: stage iter 0 into buffer 0
#pragma unroll
    for (int i = 0; i < 3; ++i) {
        const int c = w * 3 + i, j = c >> 1, kg2 = c & 1;
        gld16((char*)wsW[0] + (size_t)c * 1024 + lane * 16,
              (const char*)wF + ((size_t)(j * 24 + kg2) * 64 + lane) * 16);
    }
    {
        float4 xv = *(const float4*)&x[(size_t)(m0 + xrow) * 768 + xc16 * 4];
        *(uint2*)&xs[0][xrow][xc16 * 4] =
            (uint2){cvtpk_bf16(xv.x, xv.y), cvtpk_bf16(xv.z, xv.w)};
    }
    __syncthreads();

    for (int kk = 0; kk < 12; ++kk) {
        const int cur = kk & 1, nxt = cur ^ 1;
        float4 xn;
        if (kk + 1 < 12) {
            // prefetch next W slice (async -> LDS) and next x tile (-> regs)
#pragma unroll
            for (int i = 0; i < 3; ++i) {
                const int c = w * 3 + i, j = c >> 1, kg2 = c & 1;
                gld16((char*)wsW[nxt] + (size_t)c * 1024 + lane * 16,
                      (const char*)wF + ((size_t)(j * 24 + (kk + 1) * 2 + kg2) * 64 + lane) * 16);
            }
            xn = *(const float4*)&x[(size_t)(m0 + xrow) * 768 + (kk + 1) * 64 + xc16 * 4];
        }

        // compute current buffer: A-frag is a single b128 LDS read (bf16)
#pragma unroll
        for (int kg2 = 0; kg2 < 2; ++kg2) {
            ABu af;
            af.u = *(const uint4*)&xs[cur][mh * 16 + l16][kg2 * 32 + quad * 8];
#pragma unroll
            for (int jl = 0; jl < 3; ++jl) {
                const int j = nh * 3 + jl;
                ABu bf;
                bf.u = *(const uint4*)((char*)wsW[cur] + (size_t)(j * 2 + kg2) * 1024 + lane * 16);
                acc[jl] = __builtin_amdgcn_mfma_f32_16x16x32_bf16(af.v, bf.v, acc[jl], 0, 0, 0);
            }
        }

        if (kk + 1 < 12)
            *(uint2*)&xs[nxt][xrow][xc16 * 4] =
                (uint2){cvtpk_bf16(xn.x, xn.y), cvtpk_bf16(xn.z, xn.w)};
        __syncthreads();   // drains prefetch; protects cur for next overwrite
    }

    // ---- epilogue: C-frags -> Cst (bf16) -> fragment-major stores ----
#pragma unroll
    for (int jl = 0; jl < 3; ++jl)
#pragma unroll
        for (int r = 0; r < 4; ++r)
            Cst[mh][nh * 3 + jl][quad * 4 + r][l16] = f2bf(acc[jl][r]);
    __syncthreads();

    const int g = tid >> 6, el = tid & 63;
    const int eq = el >> 4, e16 = el & 15;
    if (g < 4) {   // Q and K frags
        const int mhh = g >> 1, kg = g & 1;
        ABu oq, ok;
#pragma unroll
        for (int i = 0; i < 8; ++i) {
            const int h = kg * 32 + eq * 8 + i;
            oq.us[i] = Cst[mhh][h >> 4][e16][h & 15];
            ok.us[i] = Cst[mhh][4 + (h >> 4)][e16][h & 15];
        }
        const size_t tt = (size_t)b * 128 + ((m0 & 2047) >> 4) + mhh;
        *(uint4*)(qF + ((tt * 2 + kg) * 64 + el) * 8) = oq.u;
        *(uint4*)(kF + ((tt * 2 + kg) * 64 + el) * 8) = ok.u;
    } else {       // V frags
        const int nt = g & 3;
        const int sv = (m0 & 2047) >> 6, kg = (m0 >> 5) & 1;
        ABu ov;
#pragma unroll
        for (int i = 0; i < 8; ++i) {
            const int loc = eq * 8 + i;
            ov.us[i] = Cst[loc >> 4][8 + nt][loc & 15][e16];
        }
        *(uint4*)(vF + ((((size_t)(b * 32 + sv) * 4 + nt) * 2 + kg) * 64 + el) * 8) = ov.u;
    }
}

// ---------------------------------------------------------------------------
// Kernel 3: flash attention, barrier-free, zero-LDS. 1024 blocks x 256 thr.
// Swapped QK^T (S^T), in-register P transpose, mask only diagonal tile,
// row-sum via ones-MFMA, XCD-balanced (b, qs, quarter) mapping.
// ---------------------------------------------------------------------------
template<bool MASKED>
__device__ __forceinline__ void attn_tile(
    const int st, const int b, const int tq0,
    const int lane, const int l16, const int quad,
    const ABu& aq0, const ABu& aq1, const ABu& onesb,
    const unsigned short* __restrict__ kF,
    const unsigned short* __restrict__ vF,
    f32x4 acc[4], f32x4& lacc)
{
    const float SC = 0.125f * 1.44269504089f;   // scale * log2(e)
    const float MB = 16.0f  * 1.44269504089f;   // fixed-max * log2(e)
    const int s0 = st * 64;
    const unsigned short* kbase = kF + (size_t)(b * 128 + st * 4) * 1024;
    const unsigned short* vbase = vF + (size_t)(b * 32 + st) * 4096;

    ABu kf[8];
#pragma unroll
    for (int c = 0; c < 8; ++c)
        kf[c].u = *(const uint4*)(kbase + (size_t)c * 512 + lane * 8);

    float p[4][4];
#pragma unroll
    for (int nt = 0; nt < 4; ++nt) {
        f32x4 s = (f32x4){0.f, 0.f, 0.f, 0.f};
        // swapped operands: A = K-frag (rows = s), B = Q-frag (cols = q)
        s = __builtin_amdgcn_mfma_f32_16x16x32_bf16(kf[nt * 2 + 0].v, aq0.v, s, 0, 0, 0);
        s = __builtin_amdgcn_mfma_f32_16x16x32_bf16(kf[nt * 2 + 1].v, aq1.v, s, 0, 0, 0);
#pragma unroll
        for (int r = 0; r < 4; ++r) {
            float pv = __builtin_amdgcn_exp2f(__builtin_fmaf(s[r], SC, -MB));
            if (MASKED)
                pv = (s0 + nt * 16 + quad * 4 + r > tq0 + l16) ? 0.f : pv;
            p[nt][r] = pv;
        }
    }

    ABu vf[8];
#pragma unroll
    for (int c = 0; c < 8; ++c)
        vf[c].u = *(const uint4*)(vbase + (size_t)c * 512 + lane * 8);

    // P (S^T C-layout) -> PV A-frags, fully in-register.
    // af[ks].us[j] = P[q=l16][s = ks*32 + quad*8 + j].
    ABu af[2];
#pragma unroll
    for (int ks = 0; ks < 2; ++ks) {
        u32 x0 = cvtpk_bf16(p[2 * ks][0], p[2 * ks][1]);
        u32 x1 = cvtpk_bf16(p[2 * ks][2], p[2 * ks][3]);
        u32 y0 = cvtpk_bf16(p[2 * ks + 1][0], p[2 * ks + 1][1]);
        u32 y1 = cvtpk_bf16(p[2 * ks + 1][2], p[2 * ks + 1][3]);
        asm("v_permlane32_swap_b32 %0, %1" : "+v"(x0), "+v"(y0));
        asm("v_permlane16_swap_b32 %0, %1" : "+v"(x0), "+v"(y0));
        asm("v_permlane32_swap_b32 %0, %1" : "+v"(x1), "+v"(y1));
        asm("v_permlane16_swap_b32 %0, %1" : "+v"(x1), "+v"(y1));
        af[ks].u = (uint4){x0, x1, y0, y1};
    }

#pragma unroll
    for (int nt = 0; nt < 4; ++nt) {
        acc[nt] = __builtin_amdgcn_mfma_f32_16x16x32_bf16(af[0].v, vf[nt * 2 + 0].v, acc[nt], 0, 0, 0);
        acc[nt] = __builtin_amdgcn_mfma_f32_16x16x32_bf16(af[1].v, vf[nt * 2 + 1].v, acc[nt], 0, 0, 0);
    }
    // row-sum of (rounded) P via ones-MFMA: lacc[r] = l[q=quad*4+r], all cols equal
    lacc = __builtin_amdgcn_mfma_f32_16x16x32_bf16(af[0].v, onesb.v, lacc, 0, 0, 0);
    lacc = __builtin_amdgcn_mfma_f32_16x16x32_bf16(af[1].v, onesb.v, lacc, 0, 0, 0);
}

__global__ __launch_bounds__(256, 4)
void attn_kernel(const unsigned short* __restrict__ qF,
                 const unsigned short* __restrict__ kF,
                 const unsigned short* __restrict__ vF,
                 unsigned short* __restrict__ opart, float* __restrict__ lpart) {
    const int tid  = threadIdx.x;
    const int lane = tid & 63, w = tid >> 6;
    const int l16  = lane & 15, quad = lane >> 4;
    const int idx  = blockIdx.x;
    // XCD-balanced mapping: XCD = idx&7 (empirical round-robin) -> batch b, so
    // each XCD's 512KB K/V slice is L2-resident. From hi = idx>>3, a CU's 4
    // resident blocks (breadth-first fill: hi stride 32) get qs set
    // {v, 31-v, v+8, 23-v} and one quarter each -> 16-18 iters per CU (tight),
    // vs old map's 2.9x per-XCD skew (XCDs 0-3 light-only, 4-7 heavy-only).
    const int b    = idx & 7;
    const int hi   = idx >> 3;               // 0..127
    const int quarter = hi & 3;
    const int g    = (hi >> 2) & 7;
    const int tr   = hi >> 5;                // 0..3
    const int v    = g + ((tr >> 1) << 3);
    const int qs   = (tr & 1) ? (31 - v) : v;
    const int tt   = qs * 4 + w;
    const int tq0  = tt * 16;

    ABu aq0, aq1, onesb;
    aq0.u = *(const uint4*)(qF + ((((size_t)b * 128 + tt) * 2 + 0) * 64 + lane) * 8);
    aq1.u = *(const uint4*)(qF + ((((size_t)b * 128 + tt) * 2 + 1) * 64 + lane) * 8);
    onesb.u = (uint4){0x3F803F80u, 0x3F803F80u, 0x3F803F80u, 0x3F803F80u};  // bf16 1.0 x8

    f32x4 acc[4];
#pragma unroll
    for (int nt = 0; nt < 4; ++nt) acc[nt] = (f32x4){0.f, 0.f, 0.f, 0.f};
    f32x4 lacc = (f32x4){0.f, 0.f, 0.f, 0.f};

    int st = quarter;
    for (; st < qs; st += 4)
        attn_tile<false>(st, b, tq0, lane, l16, quad, aq0, aq1, onesb, kF, vF, acc, lacc);
    if (st == qs)
        attn_tile<true>(st, b, tq0, lane, l16, quad, aq0, aq1, onesb, kF, vF, acc, lacc);

    // ---- epilogue: bf16 partial-O, fp32 partial-l ----
    unsigned short* obase = opart + ((size_t)(quarter * 8 + b) * 2048 + tq0) * 64;
#pragma unroll
    for (int nt = 0; nt < 4; ++nt)
#pragma unroll
        for (int r = 0; r < 4; ++r)
            obase[(size_t)(quad * 4 + r) * 64 + nt * 16 + l16] = f2bf(acc[nt][r]);
    if (l16 == 0) {
#pragma unroll
        for (int r = 0; r < 4; ++r)
            lpart[(size_t)(quarter * 8 + b) * 2048 + tq0 + quad * 4 + r] = lacc[r];
    }
}

// ---------------------------------------------------------------------------
// Kernel 4: finalize — out = (sum of 4 bf16 partial O) / (sum of 4 partial l).
// ---------------------------------------------------------------------------
__global__ __launch_bounds__(256)
void finalize_kernel(const unsigned short* __restrict__ opart,
                     const float* __restrict__ lpart, float* __restrict__ out) {
    const int idx = blockIdx.x * 256 + threadIdx.x;     // 4-elem group, 262144 total
    const int row = idx >> 4;
    float4 v = (float4){0.f, 0.f, 0.f, 0.f};
    float  l = 0.f;
#pragma unroll
    for (int q = 0; q < 4; ++q) {
        ushort4 u = ((const ushort4*)opart)[(size_t)q * 262144 + idx];
        v.x += bf2f(u.x); v.y += bf2f(u.y); v.z += bf2f(u.z); v.w += bf2f(u.w);
        l += lpart[(size_t)q * 16384 + row];
    }
    const float li = 1.f / l;
    v.x *= li; v.y *= li; v.z *= li; v.w *= li;
    ((float4*)out)[idx] = v;
}

// ---------------------------------------------------------------------------
extern "C" void kernel_launch(void* const* d_in, const int* in_sizes, int n_in,
                              void* d_out, int out_size, void* d_ws, size_t ws_size,
                              hipStream_t stream) {
    const float* x  = (const float*)d_in[0];
    const float* Wq = (const float*)d_in[1];
    const float* Wk = (const float*)d_in[2];
    const float* Wv = (const float*)d_in[3];
    float* out = (float*)d_out;

    char* ws = (char*)d_ws;
    unsigned short* wF    = (unsigned short*)ws;                              // 288 KB
    unsigned short* qF    = (unsigned short*)(ws + (512 << 10));              // 2 MB
    unsigned short* kF    = (unsigned short*)(ws + (512 << 10) + (2 << 20));  // 2 MB
    unsigned short* vF    = (unsigned short*)(ws + (512 << 10) + (4 << 20));  // 2 MB
    unsigned short* opart = (unsigned short*)(ws + (512 << 10) + (6 << 20));  // 8 MB bf16
    float*          lpart = (float*)(ws + (512 << 10) + (14 << 20));          // 256 KB

    wt_kernel<<<72, 256, 0, stream>>>(Wq, Wk, Wv, wF);
    qkv_kernel<<<512, 512, 0, stream>>>(x, wF, qF, kF, vF);
    attn_kernel<<<1024, 256, 0, stream>>>(qF, kF, vF, opart, lpart);
    finalize_kernel<<<1024, 256, 0, stream>>>(opart, lpart, out);
}

// Round 6
// 117.224 us; speedup vs baseline: 1.0942x; 1.0009x over previous
//
#include <hip/hip_runtime.h>

// B=8, T=2048, C=768, H=64. x fp32 [B,T,C]; Wq/Wk/Wv fp32 [C,H]; out fp32 [B,T,H].
// R15: R13 control flow (proven correct) + two safe levers from the R14 theory:
//      (a) attn __launch_bounds__(256,2) — old (256,4) forced a 128-VGPR cap on
//          a ~140-VGPR kernel (inner-loop spills); (b) V-loads hoisted above the
//          QK^T/softmax block (straight-line reorder, loads clump -> latency
//          hidden under MFMA+exp chain). R14's cross-tile pipeline (failed
//          correctness, suspected regalloc miscompile) is reverted.

typedef __bf16 bf16x8 __attribute__((ext_vector_type(8)));
typedef float  f32x4  __attribute__((ext_vector_type(4)));
typedef unsigned int u32;

union ABu {
    bf16x8 v;
    uint4  u;
    unsigned short us[8];
};

__device__ __forceinline__ unsigned short f2bf(float f) {
    union { __bf16 h; unsigned short s; } c;
    c.h = (__bf16)f;          // RNE
    return c.s;
}
__device__ __forceinline__ float bf2f(unsigned short s) {
    union { unsigned int u; float f; } c; c.u = ((unsigned int)s) << 16;
    return c.f;
}
// packed fp32x2 -> bf16x2 (RNE), low half = lo
__device__ __forceinline__ u32 cvtpk_bf16(float lo, float hi) {
    u32 r;
    asm("v_cvt_pk_bf16_f32 %0, %1, %2" : "=v"(r) : "v"(lo), "v"(hi));
    return r;
}

// async global->LDS, 16B per lane; dst must be wave-uniform base + lane*16
__device__ __forceinline__ void gld16(void* lds, const void* g) {
    __builtin_amdgcn_global_load_lds(
        (const u32 __attribute__((address_space(1)))*)g,
        (u32 __attribute__((address_space(3)))*)lds, 16, 0, 0);
}

// ---------------------------------------------------------------------------
// Kernel 1: W [768][64] fp32 -> wF fragment-major bf16.
// ---------------------------------------------------------------------------
__global__ __launch_bounds__(256)
void wt_kernel(const float* __restrict__ Wq, const float* __restrict__ Wk,
               const float* __restrict__ Wv, unsigned short* __restrict__ wF) {
    const int j   = blockIdx.x / 6;
    const int kgg = blockIdx.x % 6;
    const int t = threadIdx.x;
    const int kg = kgg * 4 + (t >> 6);
    const int lane = t & 63, quad = lane >> 4, l16 = lane & 15;
    const int m = j >> 2, nb = (j & 3) * 16;
    const float* W = (m == 0) ? Wq : (m == 1) ? Wk : Wv;
    ABu o;
#pragma unroll
    for (int i = 0; i < 8; ++i)
        o.us[i] = f2bf(W[(kg * 32 + quad * 8 + i) * 64 + nb + l16]);
    *(uint4*)(wF + ((size_t)(j * 24 + kg) * 64 + lane) * 8) = o.u;
}

// ---------------------------------------------------------------------------
// Kernel 2: QKV GEMM, double-buffered. 512 blocks x 512 threads (8 waves).
// x staged in LDS as bf16 (single conversion at staging). LDS 70.3 KB -> 2/CU.
// ---------------------------------------------------------------------------
__global__ __launch_bounds__(512, 4)
void qkv_kernel(const float* __restrict__ x, const unsigned short* __restrict__ wF,
                unsigned short* __restrict__ qF, unsigned short* __restrict__ kF,
                unsigned short* __restrict__ vF) {
    __shared__ unsigned short xs[2][32][72];          // 9.2 KB bf16 (144B rows, 16B-aligned)
    __shared__ unsigned short wsW[2][24][64][8];      // 48 KB
    __shared__ unsigned short Cst[2][12][16][17];     // 13.1 KB
    const int tid  = threadIdx.x;
    const int lane = tid & 63, w = tid >> 6;
    const int l16  = lane & 15, quad = lane >> 4;
    const int mh   = w & 1, nh = w >> 1;
    const int m0   = blockIdx.x * 32;
    const int b    = m0 >> 11;

    f32x4 acc[3];
#pragma unroll
    for (int j = 0; j < 3; ++j) acc[j] = (f32x4){0.f, 0.f, 0.f, 0.f};

    const int xrow = tid >> 4, xc16 = tid & 15;       // 512 thr = 32 rows x 16 float4

    // prologue: stage iter 0 into buffer 0
#pragma unroll
    for (int i = 0; i < 3; ++i) {
        const int c = w * 3 + i, j = c >> 1, kg2 = c & 1;
        gld16((char*)wsW[0] + (size_t)c * 1024 + lane * 16,
              (const char*)wF + ((size_t)(j * 24 + kg2) * 64 + lane) * 16);
    }
    {
        float4 xv = *(const float4*)&x[(size_t)(m0 + xrow) * 768 + xc16 * 4];
        *(uint2*)&xs[0][xrow][xc16 * 4] =
            (uint2){cvtpk_bf16(xv.x, xv.y), cvtpk_bf16(xv.z, xv.w)};
    }
    __syncthreads();

    for (int kk = 0; kk < 12; ++kk) {
        const int cur = kk & 1, nxt = cur ^ 1;
        float4 xn;
        if (kk + 1 < 12) {
            // prefetch next W slice (async -> LDS) and next x tile (-> regs)
#pragma unroll
            for (int i = 0; i < 3; ++i) {
                const int c = w * 3 + i, j = c >> 1, kg2 = c & 1;
                gld16((char*)wsW[nxt] + (size_t)c * 1024 + lane * 16,
                      (const char*)wF + ((size_t)(j * 24 + (kk + 1) * 2 + kg2) * 64 + lane) * 16);
            }
            xn = *(const float4*)&x[(size_t)(m0 + xrow) * 768 + (kk + 1) * 64 + xc16 * 4];
        }

        // compute current buffer: A-frag is a single b128 LDS read (bf16)
#pragma unroll
        for (int kg2 = 0; kg2 < 2; ++kg2) {
            ABu af;
            af.u = *(const uint4*)&xs[cur][mh * 16 + l16][kg2 * 32 + quad * 8];
#pragma unroll
            for (int jl = 0; jl < 3; ++jl) {
                const int j = nh * 3 + jl;
                ABu bf;
                bf.u = *(const uint4*)((char*)wsW[cur] + (size_t)(j * 2 + kg2) * 1024 + lane * 16);
                acc[jl] = __builtin_amdgcn_mfma_f32_16x16x32_bf16(af.v, bf.v, acc[jl], 0, 0, 0);
            }
        }

        if (kk + 1 < 12)
            *(uint2*)&xs[nxt][xrow][xc16 * 4] =
                (uint2){cvtpk_bf16(xn.x, xn.y), cvtpk_bf16(xn.z, xn.w)};
        __syncthreads();   // drains prefetch; protects cur for next overwrite
    }

    // ---- epilogue: C-frags -> Cst (bf16) -> fragment-major stores ----
#pragma unroll
    for (int jl = 0; jl < 3; ++jl)
#pragma unroll
        for (int r = 0; r < 4; ++r)
            Cst[mh][nh * 3 + jl][quad * 4 + r][l16] = f2bf(acc[jl][r]);
    __syncthreads();

    const int g = tid >> 6, el = tid & 63;
    const int eq = el >> 4, e16 = el & 15;
    if (g < 4) {   // Q and K frags
        const int mhh = g >> 1, kg = g & 1;
        ABu oq, ok;
#pragma unroll
        for (int i = 0; i < 8; ++i) {
            const int h = kg * 32 + eq * 8 + i;
            oq.us[i] = Cst[mhh][h >> 4][e16][h & 15];
            ok.us[i] = Cst[mhh][4 + (h >> 4)][e16][h & 15];
        }
        const size_t tt = (size_t)b * 128 + ((m0 & 2047) >> 4) + mhh;
        *(uint4*)(qF + ((tt * 2 + kg) * 64 + el) * 8) = oq.u;
        *(uint4*)(kF + ((tt * 2 + kg) * 64 + el) * 8) = ok.u;
    } else {       // V frags
        const int nt = g & 3;
        const int sv = (m0 & 2047) >> 6, kg = (m0 >> 5) & 1;
        ABu ov;
#pragma unroll
        for (int i = 0; i < 8; ++i) {
            const int loc = eq * 8 + i;
            ov.us[i] = Cst[loc >> 4][8 + nt][loc & 15][e16];
        }
        *(uint4*)(vF + ((((size_t)(b * 32 + sv) * 4 + nt) * 2 + kg) * 64 + el) * 8) = ov.u;
    }
}

// ---------------------------------------------------------------------------
// Kernel 3: flash attention, barrier-free, zero-LDS. 1024 blocks x 256 thr.
// Swapped QK^T (S^T), in-register P transpose, mask only diagonal tile,
// row-sum via ones-MFMA, XCD-balanced (b, qs, quarter) mapping.
// R13 control flow; V-loads hoisted above QK^T; launch_bounds relaxed.
// ---------------------------------------------------------------------------
template<bool MASKED>
__device__ __forceinline__ void attn_tile(
    const int st, const int b, const int tq0,
    const int lane, const int l16, const int quad,
    const ABu& aq0, const ABu& aq1, const ABu& onesb,
    const unsigned short* __restrict__ kF,
    const unsigned short* __restrict__ vF,
    f32x4 acc[4], f32x4& lacc)
{
    const float SC = 0.125f * 1.44269504089f;   // scale * log2(e)
    const float MB = 16.0f  * 1.44269504089f;   // fixed-max * log2(e)
    const int s0 = st * 64;
    const unsigned short* kbase = kF + (size_t)(b * 128 + st * 4) * 1024;
    const unsigned short* vbase = vF + (size_t)(b * 32 + st) * 4096;

    // issue all 16 K/V loads up front: V latency hides under QK^T + softmax
    ABu kf[8];
#pragma unroll
    for (int c = 0; c < 8; ++c)
        kf[c].u = *(const uint4*)(kbase + (size_t)c * 512 + lane * 8);
    ABu vf[8];
#pragma unroll
    for (int c = 0; c < 8; ++c)
        vf[c].u = *(const uint4*)(vbase + (size_t)c * 512 + lane * 8);

    float p[4][4];
#pragma unroll
    for (int nt = 0; nt < 4; ++nt) {
        f32x4 s = (f32x4){0.f, 0.f, 0.f, 0.f};
        // swapped operands: A = K-frag (rows = s), B = Q-frag (cols = q)
        s = __builtin_amdgcn_mfma_f32_16x16x32_bf16(kf[nt * 2 + 0].v, aq0.v, s, 0, 0, 0);
        s = __builtin_amdgcn_mfma_f32_16x16x32_bf16(kf[nt * 2 + 1].v, aq1.v, s, 0, 0, 0);
#pragma unroll
        for (int r = 0; r < 4; ++r) {
            float pv = __builtin_amdgcn_exp2f(__builtin_fmaf(s[r], SC, -MB));
            if (MASKED)
                pv = (s0 + nt * 16 + quad * 4 + r > tq0 + l16) ? 0.f : pv;
            p[nt][r] = pv;
        }
    }

    // P (S^T C-layout) -> PV A-frags, fully in-register.
    // af[ks].us[j] = P[q=l16][s = ks*32 + quad*8 + j].
    ABu af[2];
#pragma unroll
    for (int ks = 0; ks < 2; ++ks) {
        u32 x0 = cvtpk_bf16(p[2 * ks][0], p[2 * ks][1]);
        u32 x1 = cvtpk_bf16(p[2 * ks][2], p[2 * ks][3]);
        u32 y0 = cvtpk_bf16(p[2 * ks + 1][0], p[2 * ks + 1][1]);
        u32 y1 = cvtpk_bf16(p[2 * ks + 1][2], p[2 * ks + 1][3]);
        asm("v_permlane32_swap_b32 %0, %1" : "+v"(x0), "+v"(y0));
        asm("v_permlane16_swap_b32 %0, %1" : "+v"(x0), "+v"(y0));
        asm("v_permlane32_swap_b32 %0, %1" : "+v"(x1), "+v"(y1));
        asm("v_permlane16_swap_b32 %0, %1" : "+v"(x1), "+v"(y1));
        af[ks].u = (uint4){x0, x1, y0, y1};
    }

#pragma unroll
    for (int nt = 0; nt < 4; ++nt) {
        acc[nt] = __builtin_amdgcn_mfma_f32_16x16x32_bf16(af[0].v, vf[nt * 2 + 0].v, acc[nt], 0, 0, 0);
        acc[nt] = __builtin_amdgcn_mfma_f32_16x16x32_bf16(af[1].v, vf[nt * 2 + 1].v, acc[nt], 0, 0, 0);
    }
    // row-sum of (rounded) P via ones-MFMA: lacc[r] = l[q], all cols equal
    lacc = __builtin_amdgcn_mfma_f32_16x16x32_bf16(af[0].v, onesb.v, lacc, 0, 0, 0);
    lacc = __builtin_amdgcn_mfma_f32_16x16x32_bf16(af[1].v, onesb.v, lacc, 0, 0, 0);
}

__global__ __launch_bounds__(256, 2)
void attn_kernel(const unsigned short* __restrict__ qF,
                 const unsigned short* __restrict__ kF,
                 const unsigned short* __restrict__ vF,
                 unsigned short* __restrict__ opart, float* __restrict__ lpart) {
    const int tid  = threadIdx.x;
    const int lane = tid & 63, w = tid >> 6;
    const int l16  = lane & 15, quad = lane >> 4;
    const int idx  = blockIdx.x;
    // XCD-balanced mapping: XCD = idx&7 -> batch b (K/V slice L2-resident);
    // hi -> (quarter, qs) such that co-resident blocks mix heavy/light rows.
    const int b    = idx & 7;
    const int hi   = idx >> 3;               // 0..127
    const int quarter = hi & 3;
    const int g    = (hi >> 2) & 7;
    const int tr   = hi >> 5;                // 0..3
    const int v    = g + ((tr >> 1) << 3);
    const int qs   = (tr & 1) ? (31 - v) : v;
    const int tt   = qs * 4 + w;
    const int tq0  = tt * 16;

    ABu aq0, aq1, onesb;
    aq0.u = *(const uint4*)(qF + ((((size_t)b * 128 + tt) * 2 + 0) * 64 + lane) * 8);
    aq1.u = *(const uint4*)(qF + ((((size_t)b * 128 + tt) * 2 + 1) * 64 + lane) * 8);
    onesb.u = (uint4){0x3F803F80u, 0x3F803F80u, 0x3F803F80u, 0x3F803F80u};  // bf16 1.0 x8

    f32x4 acc[4];
#pragma unroll
    for (int nt = 0; nt < 4; ++nt) acc[nt] = (f32x4){0.f, 0.f, 0.f, 0.f};
    f32x4 lacc = (f32x4){0.f, 0.f, 0.f, 0.f};

    int st = quarter;
    for (; st < qs; st += 4)
        attn_tile<false>(st, b, tq0, lane, l16, quad, aq0, aq1, onesb, kF, vF, acc, lacc);
    if (st == qs)
        attn_tile<true>(st, b, tq0, lane, l16, quad, aq0, aq1, onesb, kF, vF, acc, lacc);

    // ---- epilogue: bf16 partial-O, fp32 partial-l ----
    unsigned short* obase = opart + ((size_t)(quarter * 8 + b) * 2048 + tq0) * 64;
#pragma unroll
    for (int nt = 0; nt < 4; ++nt)
#pragma unroll
        for (int r = 0; r < 4; ++r)
            obase[(size_t)(quad * 4 + r) * 64 + nt * 16 + l16] = f2bf(acc[nt][r]);
    if (l16 == 0) {
#pragma unroll
        for (int r = 0; r < 4; ++r)
            lpart[(size_t)(quarter * 8 + b) * 2048 + tq0 + quad * 4 + r] = lacc[r];
    }
}

// ---------------------------------------------------------------------------
// Kernel 4: finalize — out = (sum of 4 bf16 partial O) / (sum of 4 partial l).
// ---------------------------------------------------------------------------
__global__ __launch_bounds__(256)
void finalize_kernel(const unsigned short* __restrict__ opart,
                     const float* __restrict__ lpart, float* __restrict__ out) {
    const int idx = blockIdx.x * 256 + threadIdx.x;     // 4-elem group, 262144 total
    const int row = idx >> 4;
    float4 v = (float4){0.f, 0.f, 0.f, 0.f};
    float  l = 0.f;
#pragma unroll
    for (int q = 0; q < 4; ++q) {
        ushort4 u = ((const ushort4*)opart)[(size_t)q * 262144 + idx];
        v.x += bf2f(u.x); v.y += bf2f(u.y); v.z += bf2f(u.z); v.w += bf2f(u.w);
        l += lpart[(size_t)q * 16384 + row];
    }
    const float li = 1.f / l;
    v.x *= li; v.y *= li; v.z *= li; v.w *= li;
    ((float4*)out)[idx] = v;
}

// ---------------------------------------------------------------------------
extern "C" void kernel_launch(void* const* d_in, const int* in_sizes, int n_in,
                              void* d_out, int out_size, void* d_ws, size_t ws_size,
                              hipStream_t stream) {
    const float* x  = (const float*)d_in[0];
    const float* Wq = (const float*)d_in[1];
    const float* Wk = (const float*)d_in[2];
    const float* Wv = (const float*)d_in[3];
    float* out = (float*)d_out;

    char* ws = (char*)d_ws;
    unsigned short* wF    = (unsigned short*)ws;                              // 288 KB
    unsigned short* qF    = (unsigned short*)(ws + (512 << 10));              // 2 MB
    unsigned short* kF    = (unsigned short*)(ws + (512 << 10) + (2 << 20));  // 2 MB
    unsigned short* vF    = (unsigned short*)(ws + (512 << 10) + (4 << 20));  // 2 MB
    unsigned short* opart = (unsigned short*)(ws + (512 << 10) + (6 << 20));  // 8 MB bf16
    float*          lpart = (float*)(ws + (512 << 10) + (14 << 20));          // 256 KB

    wt_kernel<<<72, 256, 0, stream>>>(Wq, Wk, Wv, wF);
    qkv_kernel<<<512, 512, 0, stream>>>(x, wF, qF, kF, vF);
    attn_kernel<<<1024, 256, 0, stream>>>(qF, kF, vF, opart, lpart);
    finalize_kernel<<<1024, 256, 0, stream>>>(opart, lpart, out);
}